// Round 1
// baseline (311.862 us; speedup 1.0000x reference)
//
#include <hip/hip_runtime.h>
#include <math.h>

// Sparsemax over rows: out = max(z - tau, 0), tau s.t. sum(max(z - tau, 0)) = 1.
// One block per row; row (4096 fp32) held entirely in registers (16/thread).
// tau found by 12-step bisection in [zmax-1, zmax] + exact refinement on the
// identified support set (error <= bisection interval ~2.4e-4 << 2e-2 threshold).

constexpr int S   = 4096;
constexpr int TPB = 256;
constexpr int VPT = S / TPB;   // 16 values per thread
constexpr int NW  = TPB / 64;  // 4 waves per block

#define NEGBIG (-1e30f)

__global__ __launch_bounds__(TPB) void sparsemax_kernel(
    const float* __restrict__ scores,
    const int*   __restrict__ mask,
    float*       __restrict__ out)
{
    const int row  = blockIdx.x;
    const int tid  = threadIdx.x;
    const int lane = tid & 63;
    const int wid  = tid >> 6;

    const float* srow = scores + (size_t)row * S;
    const int*   mrow = mask   + (size_t)row * S;
    float*       orow = out    + (size_t)row * S;

    float z[VPT];
    #pragma unroll
    for (int c = 0; c < VPT / 4; ++c) {
        const int idx = c * (TPB * 4) + tid * 4;
        const float4 s4 = *reinterpret_cast<const float4*>(srow + idx);
        const int4   m4 = *reinterpret_cast<const int4*>(mrow + idx);
        z[c * 4 + 0] = m4.x ? s4.x : NEGBIG;
        z[c * 4 + 1] = m4.y ? s4.y : NEGBIG;
        z[c * 4 + 2] = m4.z ? s4.z : NEGBIG;
        z[c * 4 + 3] = m4.w ? s4.w : NEGBIG;
    }

    __shared__ float red[NW];
    __shared__ float red2[NW];

    // ---- row max ----
    float m = z[0];
    #pragma unroll
    for (int j = 1; j < VPT; ++j) m = fmaxf(m, z[j]);
    #pragma unroll
    for (int o = 1; o < 64; o <<= 1) m = fmaxf(m, __shfl_xor(m, o, 64));
    if (lane == 0) red[wid] = m;
    __syncthreads();
    const float zmax = fmaxf(fmaxf(red[0], red[1]), fmaxf(red[2], red[3]));

    // ---- bisection on f(tau) = sum(max(z - tau, 0)) - 1, root in [zmax-1, zmax] ----
    float lo = zmax - 1.0f, hi = zmax;
    #pragma unroll 1
    for (int it = 0; it < 12; ++it) {
        const float mid = 0.5f * (lo + hi);
        float f = 0.0f;
        #pragma unroll
        for (int j = 0; j < VPT; ++j) f += fmaxf(z[j] - mid, 0.0f);
        #pragma unroll
        for (int o = 1; o < 64; o <<= 1) f += __shfl_xor(f, o, 64);
        __syncthreads();                 // protect red[] from previous reads
        if (lane == 0) red[wid] = f;
        __syncthreads();
        f = (red[0] + red[1]) + (red[2] + red[3]);
        if (f > 1.0f) lo = mid; else hi = mid;
    }

    // ---- exact refinement: tau = (sum_{z > tc} z - 1) / count ----
    const float tc = 0.5f * (lo + hi);
    float s = 0.0f, k = 0.0f;
    #pragma unroll
    for (int j = 0; j < VPT; ++j) {
        if (z[j] > tc) { s += z[j]; k += 1.0f; }
    }
    #pragma unroll
    for (int o = 1; o < 64; o <<= 1) {
        s += __shfl_xor(s, o, 64);
        k += __shfl_xor(k, o, 64);
    }
    __syncthreads();
    if (lane == 0) { red[wid] = s; red2[wid] = k; }
    __syncthreads();
    s = (red[0] + red[1]) + (red[2] + red[3]);
    k = (red2[0] + red2[1]) + (red2[2] + red2[3]);
    if (k < 0.5f) { k = 1.0f; s = zmax; }  // unreachable guard (>=1 valid/row)
    const float tau = (s - 1.0f) / k;

    // ---- write out ----
    #pragma unroll
    for (int c = 0; c < VPT / 4; ++c) {
        const int idx = c * (TPB * 4) + tid * 4;
        float4 o4;
        o4.x = fmaxf(z[c * 4 + 0] - tau, 0.0f);
        o4.y = fmaxf(z[c * 4 + 1] - tau, 0.0f);
        o4.z = fmaxf(z[c * 4 + 2] - tau, 0.0f);
        o4.w = fmaxf(z[c * 4 + 3] - tau, 0.0f);
        *reinterpret_cast<float4*>(orow + idx) = o4;
    }
}

extern "C" void kernel_launch(void* const* d_in, const int* in_sizes, int n_in,
                              void* d_out, int out_size, void* d_ws, size_t ws_size,
                              hipStream_t stream) {
    const float* scores = (const float*)d_in[0];
    const int*   mask   = (const int*)d_in[1];
    float*       out    = (float*)d_out;
    const int B = in_sizes[0] / S;  // 8192
    sparsemax_kernel<<<dim3(B), dim3(TPB), 0, stream>>>(scores, mask, out);
}